// Round 1
// baseline (17351.605 us; speedup 1.0000x reference)
//
#include <hip/hip_runtime.h>

#define FPS_N 32768
#define FPS_M 2048
#define FPS_B 16
#define FPS_T 1024
#define PPT (FPS_N / FPS_T)  // 32 points per thread

// One block per batch. xyz in registers (96 VGPR/thread), running dist array in
// 128 KiB static LDS (each thread owns its slots -> no barrier needed for it).
// Numerics must match numpy bit-for-bit for the argmax chain to stay on the
// reference trajectory: fp contract OFF, sum order (dxx+dyy)+dzz, strict-> /
// lowest-index tie break == np.argmax first-occurrence semantics.
__global__ __launch_bounds__(FPS_T) void fps_kernel(const float* __restrict__ pts,
                                                    float* __restrict__ out) {
#pragma clang fp contract(off)
    __shared__ float sdist[FPS_N];          // 128 KiB
    __shared__ float red_d[FPS_T / 64];
    __shared__ int   red_i[FPS_T / 64];
    __shared__ float s_pt[3];

    const int b = blockIdx.x;
    const int tid = threadIdx.x;
    const float* __restrict__ X = pts + (size_t)b * 3 * FPS_N;
    const float* __restrict__ Y = X + FPS_N;
    const float* __restrict__ Z = Y + FPS_N;
    float* __restrict__ outb = out + (size_t)b * 3 * FPS_M;

    float x[PPT], y[PPT], z[PPT];
#pragma unroll
    for (int t = 0; t < PPT; ++t) {
        int g = t * FPS_T + tid;            // lane-contiguous: coalesced + conflict-free LDS
        x[t] = X[g];
        y[t] = Y[g];
        z[t] = Z[g];
        sdist[g] = 1e10f;
    }
    // first selected index is 0 (CUDA FPS convention)
    float lx = X[0], ly = Y[0], lz = Z[0];
    __syncthreads();

    for (int s = 0; s < FPS_M; ++s) {
        // emit current selection's coords (gather output)
        if (tid == 0) {
            outb[s] = lx;
            outb[FPS_M + s] = ly;
            outb[2 * FPS_M + s] = lz;
        }

        // distance update + per-thread argmax scan (ascending global index)
        float bd = -1.0f;
        int bi = 0;
#pragma unroll
        for (int t = 0; t < PPT; ++t) {
            const int g = t * FPS_T + tid;
            float dx = x[t] - lx;
            float dy = y[t] - ly;
            float dz = z[t] - lz;
            float d = (dx * dx + dy * dy) + dz * dz;   // numpy op order, no fma
            float old = sdist[g];
            float nd = d < old ? d : old;
            if (d < old) sdist[g] = d;                 // sparse write saves LDS BW
            if (nd > bd) { bd = nd; bi = g; }          // strict > keeps lowest index
        }

        // 64-lane wave reduce: max dist, ties -> lowest index
#pragma unroll
        for (int off = 32; off > 0; off >>= 1) {
            float od = __shfl_down(bd, off);
            int   oi = __shfl_down(bi, off);
            if (od > bd || (od == bd && oi < bi)) { bd = od; bi = oi; }
        }
        const int wave = tid >> 6;
        if ((tid & 63) == 0) { red_d[wave] = bd; red_i[wave] = bi; }
        __syncthreads();

        // cross-wave reduce in wave 0 (16 partials), then fetch winner coords
        if (tid < 64) {
            bd = (tid < (FPS_T / 64)) ? red_d[tid] : -1.0f;
            bi = (tid < (FPS_T / 64)) ? red_i[tid] : 0x7fffffff;
#pragma unroll
            for (int off = 8; off > 0; off >>= 1) {
                float od = __shfl_down(bd, off);
                int   oi = __shfl_down(bi, off);
                if (od > bd || (od == bd && oi < bi)) { bd = od; bi = oi; }
            }
            const int win = __shfl(bi, 0);
            if (tid == 0)      s_pt[0] = X[win];
            else if (tid == 1) s_pt[1] = Y[win];
            else if (tid == 2) s_pt[2] = Z[win];
        }
        __syncthreads();
        lx = s_pt[0];
        ly = s_pt[1];
        lz = s_pt[2];
        // no barrier needed here: s_pt is next written only after the
        // red_d/red_i __syncthreads of the next iteration.
    }
}

extern "C" void kernel_launch(void* const* d_in, const int* in_sizes, int n_in,
                              void* d_out, int out_size, void* d_ws, size_t ws_size,
                              hipStream_t stream) {
    const float* pts = (const float*)d_in[0];   // [16, 3, 32768] fp32
    float* out = (float*)d_out;                 // [16, 3, 2048] fp32
    hipLaunchKernelGGL(fps_kernel, dim3(FPS_B), dim3(FPS_T), 0, stream, pts, out);
}

// Round 2
// 8958.047 us; speedup vs baseline: 1.9370x; 1.9370x over previous
//
#include <hip/hip_runtime.h>

#define FPS_N 32768
#define FPS_M 2048
#define FPS_B 16
#define FPS_T 1024
#define NPAIR (FPS_N / 2)      // 16384 float2 pairs
#define KPT (NPAIR / FPS_T)    // 16 pairs per thread
#define NWAVE (FPS_T / 64)     // 16 waves

// One block per batch (sequential algorithm -> 16 CUs active, rest idle by
// construction). Coords register-resident: 96 VGPRs (launch_bounds(1024,4)
// -> 1 block/CU, 128-VGPR cap; round-1's default cap of 64 forced reloads
// from L2 every step = 17 ms). Running dist in 128 KiB LDS as float2, b64
// reads/writes. One barrier per step: per-wave partials double-buffered,
// every thread re-reduces the 16 partials itself (LDS broadcast reads) and
// fetches winner coords via same-address load (one L2 request per wave).
// Numerics must match numpy bit-exactly (argmax trajectory): fp contract
// off, sum order (dx*dx + dy*dy) + dz*dz, strict-> / lowest-index ties.
__global__ __launch_bounds__(FPS_T, 4) void fps_kernel(const float* __restrict__ pts,
                                                       float* __restrict__ out) {
#pragma clang fp contract(off)
    __shared__ float2 sdist[NPAIR];        // 128 KiB
    __shared__ float red_d[2][NWAVE];
    __shared__ int   red_i[2][NWAVE];

    const int b = blockIdx.x;
    const int tid = threadIdx.x;
    const float* __restrict__ X = pts + (size_t)b * 3 * FPS_N;
    const float* __restrict__ Y = X + FPS_N;
    const float* __restrict__ Z = Y + FPS_N;
    const float2* __restrict__ X2 = (const float2*)X;
    const float2* __restrict__ Y2 = (const float2*)Y;
    const float2* __restrict__ Z2 = (const float2*)Z;
    float* __restrict__ outb = out + (size_t)b * 3 * FPS_M;

    float2 x[KPT], y[KPT], z[KPT];
#pragma unroll
    for (int k = 0; k < KPT; ++k) {
        const int q = k * FPS_T + tid;     // coalesced float2 loads
        x[k] = X2[q];
        y[k] = Y2[q];
        z[k] = Z2[q];
        sdist[q] = make_float2(1e10f, 1e10f);
    }
    // first selected index is 0 (CUDA FPS convention)
    float lx = X[0], ly = Y[0], lz = Z[0];
    __syncthreads();

    for (int s = 0; s < FPS_M; ++s) {
        // emit previous selection's coords (== gather of selected index)
        if (tid == 0) {
            outb[s] = lx;
            outb[FPS_M + s] = ly;
            outb[2 * FPS_M + s] = lz;
        }

        // distance update + per-thread argmax (ascending point index per thread)
        float bd = -1.0f;
        int bi = 0;
#pragma unroll
        for (int k = 0; k < KPT; ++k) {
            const int q = k * FPS_T + tid;
            float2 dv = sdist[q];
            float dx0 = x[k].x - lx, dy0 = y[k].y - ly, dz0 = z[k].x - lz;
            // NOTE: careful — use matching components:
            dx0 = x[k].x - lx; dy0 = y[k].x - ly; dz0 = z[k].x - lz;
            float d0 = (dx0 * dx0 + dy0 * dy0) + dz0 * dz0;   // numpy op order
            float dx1 = x[k].y - lx, dy1 = y[k].y - ly, dz1 = z[k].y - lz;
            float d1 = (dx1 * dx1 + dy1 * dy1) + dz1 * dz1;
            float nd0 = d0 < dv.x ? d0 : dv.x;                 // min(dist, d)
            float nd1 = d1 < dv.y ? d1 : dv.y;
            sdist[q] = make_float2(nd0, nd1);
            if (nd0 > bd) { bd = nd0; bi = 2 * q; }            // strict >: lowest idx
            if (nd1 > bd) { bd = nd1; bi = 2 * q + 1; }
        }

        // 64-lane wave reduce: max dist, ties -> lowest index
#pragma unroll
        for (int off = 32; off > 0; off >>= 1) {
            float od = __shfl_down(bd, off);
            int   oi = __shfl_down(bi, off);
            if (od > bd || (od == bd && oi < bi)) { bd = od; bi = oi; }
        }
        const int wave = tid >> 6;
        const int par = s & 1;
        if ((tid & 63) == 0) { red_d[par][wave] = bd; red_i[par][wave] = bi; }
        __syncthreads();

        // every thread reduces the 16 wave partials (LDS broadcast reads);
        // double-buffered by step parity -> no second barrier needed.
        float wbd = red_d[par][0];
        int   wbi = red_i[par][0];
#pragma unroll
        for (int w = 1; w < NWAVE; ++w) {
            float od = red_d[par][w];
            int   oi = red_i[par][w];
            if (od > wbd || (od == wbd && oi < wbi)) { wbd = od; wbi = oi; }
        }

        // winner coords: same-address load -> one L2 request per wave
        lx = X[wbi];
        ly = Y[wbi];
        lz = Z[wbi];
    }
}

extern "C" void kernel_launch(void* const* d_in, const int* in_sizes, int n_in,
                              void* d_out, int out_size, void* d_ws, size_t ws_size,
                              hipStream_t stream) {
    const float* pts = (const float*)d_in[0];   // [16, 3, 32768] fp32
    float* out = (float*)d_out;                 // [16, 3, 2048] fp32
    hipLaunchKernelGGL(fps_kernel, dim3(FPS_B), dim3(FPS_T), 0, stream, pts, out);
}